// Round 1
// baseline (1958.439 us; speedup 1.0000x reference)
//
#include <hip/hip_runtime.h>

#define N_NODES 100000
#define N_EDGES 3200000
#define DIN 128
#define HID 64
#define N_GRAPH 256

// ---------------- degree ----------------
__global__ __launch_bounds__(256) void k_deg(const int* __restrict__ col,
                                             int* __restrict__ degi) {
  int i = blockIdx.x * 256 + threadIdx.x;
  if (i < N_EDGES) atomicAdd(&degi[col[i]], 1);
}

__global__ __launch_bounds__(256) void k_dinv(const int* __restrict__ degi,
                                              float* __restrict__ dinv) {
  int i = blockIdx.x * 256 + threadIdx.x;
  if (i < N_NODES) dinv[i] = rsqrtf((float)(degi[i] + 1));  // +1 self loop
}

// ---------------- dense GEMM: H[row, 0:64] = X[row, 0:K] @ W[K, 64] ----------------
template <int K>
__global__ __launch_bounds__(256) void k_gemm(const float* __restrict__ X,
                                              const float* __restrict__ W,
                                              float* __restrict__ Hout) {
  __shared__ float Wl[K * HID];
  __shared__ float Xl[4][K];
  for (int i = threadIdx.x; i < K * HID; i += 256) Wl[i] = W[i];
  int row0 = blockIdx.x * 4;
  for (int i = threadIdx.x; i < 4 * K; i += 256) {
    int r = i / K, k = i - r * K;
    int row = row0 + r;
    Xl[r][k] = (row < N_NODES) ? X[(long)row * K + k] : 0.f;
  }
  __syncthreads();
  int wave = threadIdx.x >> 6, lane = threadIdx.x & 63;
  int row = row0 + wave;
  if (row >= N_NODES) return;
  float acc = 0.f;
#pragma unroll
  for (int k = 0; k < K; ++k) acc += Xl[wave][k] * Wl[k * HID + lane];
  Hout[(long)row * HID + lane] = acc;
}

// ---------------- edge scatter: agg[col] += H[row] * dinv[row]*dinv[col] ----------------
__global__ __launch_bounds__(256) void k_scatter(const float* __restrict__ H,
                                                 const int* __restrict__ ei,
                                                 const float* __restrict__ dinv,
                                                 float* __restrict__ agg) {
  int e = blockIdx.x * 4 + (threadIdx.x >> 6);
  if (e >= N_EDGES) return;
  int lane = threadIdx.x & 63;
  int r = ei[e];
  int c = ei[N_EDGES + e];
  float nrm = dinv[r] * dinv[c];
  float v = H[(long)r * HID + lane] * nrm;
  atomicAdd(&agg[(long)c * HID + lane], v);
}

// ---------------- finalize: add self-loop, bias, optional relu (in place) ----------------
template <bool RELU>
__global__ __launch_bounds__(256) void k_finalize(float* __restrict__ agg,
                                                  const float* __restrict__ H,
                                                  const float* __restrict__ dinv,
                                                  const float* __restrict__ b) {
  int i = blockIdx.x * 256 + threadIdx.x;
  if (i >= N_NODES * HID) return;
  int n = i >> 6, d = i & 63;
  float di = dinv[n];
  float v = agg[i] + H[i] * di * di + b[d];
  if (RELU) v = fmaxf(v, 0.f);
  agg[i] = v;
}

// ---------------- pooling: mean + max per sorted-batch segment ----------------
__global__ __launch_bounds__(256) void k_pool(const float* __restrict__ Hf,
                                              const int* __restrict__ batch,
                                              float* __restrict__ pooled) {
  int g = blockIdx.x;
  // lower_bound(batch, v)
  int start, end;
  {
    int lo = 0, hi = N_NODES;
    while (lo < hi) { int mid = (lo + hi) >> 1; if (batch[mid] < g) lo = mid + 1; else hi = mid; }
    start = lo;
    lo = start; hi = N_NODES;
    while (lo < hi) { int mid = (lo + hi) >> 1; if (batch[mid] < g + 1) lo = mid + 1; else hi = mid; }
    end = lo;
  }
  int lane = threadIdx.x & 63, wave = threadIdx.x >> 6;
  float sum = 0.f, mx = -INFINITY;
  for (int n = start + wave; n < end; n += 4) {
    float v = Hf[(long)n * HID + lane];
    sum += v;
    mx = fmaxf(mx, v);
  }
  __shared__ float ssum[4][HID];
  __shared__ float smax[4][HID];
  ssum[wave][lane] = sum;
  smax[wave][lane] = mx;
  __syncthreads();
  if (wave == 0) {
    sum = ssum[0][lane] + ssum[1][lane] + ssum[2][lane] + ssum[3][lane];
    mx = fmaxf(fmaxf(smax[0][lane], smax[1][lane]), fmaxf(smax[2][lane], smax[3][lane]));
    int cnt = end - start;
    float mean;
    if (cnt == 0) { mean = 0.f; mx = 0.f; }
    else mean = sum / (float)cnt;
    pooled[g * 2 * HID + lane] = mean;
    pooled[g * 2 * HID + HID + lane] = mx;
  }
}

// ---------------- MLP head: out[g] = relu(p @ fcW1 + fcb1) @ fcW2 + fcb2 ----------------
__global__ __launch_bounds__(64) void k_head(const float* __restrict__ pooled,
                                             const float* __restrict__ fcW1,
                                             const float* __restrict__ fcb1,
                                             const float* __restrict__ fcW2,
                                             const float* __restrict__ fcb2,
                                             float* __restrict__ out) {
  int g = blockIdx.x;
  int lane = threadIdx.x;  // 64 threads
  __shared__ float p[2 * HID];
  p[lane] = pooled[g * 2 * HID + lane];
  p[HID + lane] = pooled[g * 2 * HID + HID + lane];
  __syncthreads();
  float acc = fcb1[lane];
#pragma unroll
  for (int k = 0; k < 2 * HID; ++k) acc += p[k] * fcW1[k * HID + lane];
  acc = fmaxf(acc, 0.f);
  float contrib = acc * fcW2[lane];
#pragma unroll
  for (int off = 32; off > 0; off >>= 1) contrib += __shfl_down(contrib, off);
  if (lane == 0) out[g] = contrib + fcb2[0];
}

extern "C" void kernel_launch(void* const* d_in, const int* in_sizes, int n_in,
                              void* d_out, int out_size, void* d_ws, size_t ws_size,
                              hipStream_t stream) {
  const float* x    = (const float*)d_in[0];
  const int*   ei   = (const int*)d_in[1];   // [2, E] int32 (JAX default x64-off)
  const int*   bat  = (const int*)d_in[2];   // [N] sorted int32
  const float* W1   = (const float*)d_in[3];
  const float* b1   = (const float*)d_in[4];
  const float* W2   = (const float*)d_in[5];
  const float* b2   = (const float*)d_in[6];
  const float* fcW1 = (const float*)d_in[7];
  const float* fcb1 = (const float*)d_in[8];
  const float* fcW2 = (const float*)d_in[9];
  const float* fcb2 = (const float*)d_in[10];
  float* out = (float*)d_out;

  char* ws = (char*)d_ws;
  int*   degi   = (int*)(ws + 0);                       // N int
  float* dinv   = (float*)(ws + 400000);                // N f32
  float* pooled = (float*)(ws + 800000);                // G*128 f32
  float* h      = (float*)(ws + (1 << 20));             // N*64 f32 (h1 then h2)
  float* agg    = (float*)(ws + (1 << 20) + (size_t)N_NODES * HID * 4);  // N*64 f32

  const size_t nh_bytes = (size_t)N_NODES * HID * sizeof(float);

  // degrees + norm
  hipMemsetAsync(degi, 0, N_NODES * sizeof(int), stream);
  k_deg<<<(N_EDGES + 255) / 256, 256, 0, stream>>>(ei + N_EDGES, degi);
  k_dinv<<<(N_NODES + 255) / 256, 256, 0, stream>>>(degi, dinv);

  // layer 1
  k_gemm<DIN><<<(N_NODES + 3) / 4, 256, 0, stream>>>(x, W1, h);
  hipMemsetAsync(agg, 0, nh_bytes, stream);
  k_scatter<<<(N_EDGES + 3) / 4, 256, 0, stream>>>(h, ei, dinv, agg);
  k_finalize<true><<<(N_NODES * HID + 255) / 256, 256, 0, stream>>>(agg, h, dinv, b1);

  // layer 2 (gemm reads agg(=out1), writes h(=h2); then agg reused for agg2)
  k_gemm<HID><<<(N_NODES + 3) / 4, 256, 0, stream>>>(agg, W2, h);
  hipMemsetAsync(agg, 0, nh_bytes, stream);
  k_scatter<<<(N_EDGES + 3) / 4, 256, 0, stream>>>(h, ei, dinv, agg);
  k_finalize<false><<<(N_NODES * HID + 255) / 256, 256, 0, stream>>>(agg, h, dinv, b2);

  // pooling + head
  k_pool<<<N_GRAPH, 256, 0, stream>>>(agg, bat, pooled);
  k_head<<<N_GRAPH, 64, 0, stream>>>(pooled, fcW1, fcb1, fcW2, fcb2, out);
}

// Round 2
// 1009.849 us; speedup vs baseline: 1.9393x; 1.9393x over previous
//
#include <hip/hip_runtime.h>

#define N_NODES 100000
#define N_EDGES 3200000
#define DIN 128
#define HID 64
#define N_GRAPH 256

// ---------------- degree count (in-edges per destination) ----------------
__global__ __launch_bounds__(256) void k_deg(const int* __restrict__ col,
                                             int* __restrict__ degi) {
  int i = blockIdx.x * 256 + threadIdx.x;
  if (i < N_EDGES) atomicAdd(&degi[col[i]], 1);
}

__global__ __launch_bounds__(256) void k_dinv(const int* __restrict__ degi,
                                              float* __restrict__ dinv) {
  int i = blockIdx.x * 256 + threadIdx.x;
  if (i < N_NODES) dinv[i] = rsqrtf((float)(degi[i] + 1));  // +1 self loop
}

// ---------------- single-block exclusive scan of degi -> rowptr[N+1] ----------------
__global__ __launch_bounds__(256) void k_scan(const int* __restrict__ cnt,
                                              int* __restrict__ rowptr) {
  __shared__ int wsum[4];
  int lane = threadIdx.x & 63, wv = threadIdx.x >> 6;
  int carry = 0;
  for (int base = 0; base < N_NODES; base += 1024) {
    int i0 = base + threadIdx.x * 4;
    int v0 = (i0 + 0 < N_NODES) ? cnt[i0 + 0] : 0;
    int v1 = (i0 + 1 < N_NODES) ? cnt[i0 + 1] : 0;
    int v2 = (i0 + 2 < N_NODES) ? cnt[i0 + 2] : 0;
    int v3 = (i0 + 3 < N_NODES) ? cnt[i0 + 3] : 0;
    int t = v0 + v1 + v2 + v3;
    int s = t;
#pragma unroll
    for (int off = 1; off < 64; off <<= 1) {
      int u = __shfl_up(s, off);
      if (lane >= off) s += u;
    }
    if (lane == 63) wsum[wv] = s;
    __syncthreads();
    int wvoff = 0;
    for (int w = 0; w < wv; ++w) wvoff += wsum[w];
    int excl = carry + wvoff + (s - t);
    if (i0 + 0 < N_NODES) rowptr[i0 + 0] = excl;
    if (i0 + 1 < N_NODES) rowptr[i0 + 1] = excl + v0;
    if (i0 + 2 < N_NODES) rowptr[i0 + 2] = excl + v0 + v1;
    if (i0 + 3 < N_NODES) rowptr[i0 + 3] = excl + v0 + v1 + v2;
    carry += wsum[0] + wsum[1] + wsum[2] + wsum[3];
    __syncthreads();
  }
  if (threadIdx.x == 0) rowptr[N_NODES] = carry;  // == N_EDGES
}

// ---------------- CSR fill: adj[slot] = src, slots bucketed by dst ----------------
__global__ __launch_bounds__(256) void k_fill(const int* __restrict__ ei,
                                              int* __restrict__ cursor,
                                              int* __restrict__ adj) {
  int e = blockIdx.x * 256 + threadIdx.x;
  if (e >= N_EDGES) return;
  int r = ei[e];
  int c = ei[N_EDGES + e];
  int pos = atomicAdd(&cursor[c], 1);
  adj[pos] = r;
}

// ---------------- dense GEMM: Hs[row,:] = (X[row,:] @ W) * dinv[row] ----------------
template <int K>
__global__ __launch_bounds__(256) void k_gemm(const float* __restrict__ X,
                                              const float* __restrict__ W,
                                              const float* __restrict__ dinv,
                                              float* __restrict__ Hs) {
  __shared__ float Wl[K * HID];
  __shared__ float Xl[4][K];
  for (int i = threadIdx.x; i < K * HID; i += 256) Wl[i] = W[i];
  int row0 = blockIdx.x * 4;
  for (int i = threadIdx.x; i < 4 * K; i += 256) {
    int r = i / K, k = i - r * K;
    int row = row0 + r;
    Xl[r][k] = (row < N_NODES) ? X[(long)row * K + k] : 0.f;
  }
  __syncthreads();
  int wave = threadIdx.x >> 6, lane = threadIdx.x & 63;
  int row = row0 + wave;
  if (row >= N_NODES) return;
  float acc = 0.f;
#pragma unroll
  for (int k = 0; k < K; ++k) acc += Xl[wave][k] * Wl[k * HID + lane];
  Hs[(long)row * HID + lane] = acc * dinv[row];
}

// ------- gather: out[n] = act( dinv[n] * (hs[n] + sum_{src in adj[n]} hs[src]) + b ) -------
template <bool RELU>
__global__ __launch_bounds__(256) void k_gather(const float* __restrict__ hs,
                                                const int* __restrict__ rowptr,
                                                const int* __restrict__ adj,
                                                const float* __restrict__ dinv,
                                                const float* __restrict__ b,
                                                float* __restrict__ outb) {
  int n = blockIdx.x * 4 + (threadIdx.x >> 6);
  if (n >= N_NODES) return;
  int lane = threadIdx.x & 63;
  int s0 = rowptr[n], e0 = rowptr[n + 1];
  float acc = hs[(n << 6) + lane];  // self loop
  for (int j = s0; j < e0; j += 64) {
    int cnt = min(64, e0 - j);
    int myadj = (lane < cnt) ? adj[j + lane] : 0;
    int t = 0;
    for (; t + 4 <= cnt; t += 4) {
      int a0 = __shfl(myadj, t + 0);
      int a1 = __shfl(myadj, t + 1);
      int a2 = __shfl(myadj, t + 2);
      int a3 = __shfl(myadj, t + 3);
      float f0 = hs[(a0 << 6) + lane];
      float f1 = hs[(a1 << 6) + lane];
      float f2 = hs[(a2 << 6) + lane];
      float f3 = hs[(a3 << 6) + lane];
      acc += f0;
      acc += f1;
      acc += f2;
      acc += f3;
    }
    for (; t < cnt; ++t) {
      int a = __shfl(myadj, t);
      acc += hs[(a << 6) + lane];
    }
  }
  float v = dinv[n] * acc + b[lane];
  if (RELU) v = fmaxf(v, 0.f);
  outb[(n << 6) + lane] = v;
}

// ---------------- pooling: mean + max per sorted-batch segment ----------------
__global__ __launch_bounds__(256) void k_pool(const float* __restrict__ Hf,
                                              const int* __restrict__ batch,
                                              float* __restrict__ pooled) {
  int g = blockIdx.x;
  int start, end;
  {
    int lo = 0, hi = N_NODES;
    while (lo < hi) { int mid = (lo + hi) >> 1; if (batch[mid] < g) lo = mid + 1; else hi = mid; }
    start = lo;
    lo = start; hi = N_NODES;
    while (lo < hi) { int mid = (lo + hi) >> 1; if (batch[mid] < g + 1) lo = mid + 1; else hi = mid; }
    end = lo;
  }
  int lane = threadIdx.x & 63, wave = threadIdx.x >> 6;
  float sum = 0.f, mx = -INFINITY;
  for (int n = start + wave; n < end; n += 4) {
    float v = Hf[(n << 6) + lane];
    sum += v;
    mx = fmaxf(mx, v);
  }
  __shared__ float ssum[4][HID];
  __shared__ float smax[4][HID];
  ssum[wave][lane] = sum;
  smax[wave][lane] = mx;
  __syncthreads();
  if (wave == 0) {
    sum = ssum[0][lane] + ssum[1][lane] + ssum[2][lane] + ssum[3][lane];
    mx = fmaxf(fmaxf(smax[0][lane], smax[1][lane]), fmaxf(smax[2][lane], smax[3][lane]));
    int cnt = end - start;
    float mean;
    if (cnt == 0) { mean = 0.f; mx = 0.f; }
    else mean = sum / (float)cnt;
    pooled[g * 2 * HID + lane] = mean;
    pooled[g * 2 * HID + HID + lane] = mx;
  }
}

// ---------------- MLP head ----------------
__global__ __launch_bounds__(64) void k_head(const float* __restrict__ pooled,
                                             const float* __restrict__ fcW1,
                                             const float* __restrict__ fcb1,
                                             const float* __restrict__ fcW2,
                                             const float* __restrict__ fcb2,
                                             float* __restrict__ out) {
  int g = blockIdx.x;
  int lane = threadIdx.x;  // 64
  __shared__ float p[2 * HID];
  p[lane] = pooled[g * 2 * HID + lane];
  p[HID + lane] = pooled[g * 2 * HID + HID + lane];
  __syncthreads();
  float acc = fcb1[lane];
#pragma unroll
  for (int k = 0; k < 2 * HID; ++k) acc += p[k] * fcW1[k * HID + lane];
  acc = fmaxf(acc, 0.f);
  float contrib = acc * fcW2[lane];
#pragma unroll
  for (int off = 32; off > 0; off >>= 1) contrib += __shfl_down(contrib, off);
  if (lane == 0) out[g] = contrib + fcb2[0];
}

extern "C" void kernel_launch(void* const* d_in, const int* in_sizes, int n_in,
                              void* d_out, int out_size, void* d_ws, size_t ws_size,
                              hipStream_t stream) {
  const float* x    = (const float*)d_in[0];
  const int*   ei   = (const int*)d_in[1];
  const int*   bat  = (const int*)d_in[2];
  const float* W1   = (const float*)d_in[3];
  const float* b1   = (const float*)d_in[4];
  const float* W2   = (const float*)d_in[5];
  const float* b2   = (const float*)d_in[6];
  const float* fcW1 = (const float*)d_in[7];
  const float* fcb1 = (const float*)d_in[8];
  const float* fcW2 = (const float*)d_in[9];
  const float* fcb2 = (const float*)d_in[10];
  float* out = (float*)d_out;

  char* ws = (char*)d_ws;
  size_t off = 0;
  int*   degi   = (int*)(ws + off);   off += 400000;
  int*   rowptr = (int*)(ws + off);   off += 400004;  off = (off + 127) & ~127ul;
  int*   cursor = (int*)(ws + off);   off += 400000;  off = (off + 127) & ~127ul;
  float* dinv   = (float*)(ws + off); off += 400000;  off = (off + 127) & ~127ul;
  float* pooled = (float*)(ws + off); off += N_GRAPH * 2 * HID * 4; off = (off + 127) & ~127ul;
  int*   adj    = (int*)(ws + off);   off += (size_t)N_EDGES * 4;   off = (off + 127) & ~127ul;
  float* hs     = (float*)(ws + off); off += (size_t)N_NODES * HID * 4; off = (off + 127) & ~127ul;
  float* ob     = (float*)(ws + off); off += (size_t)N_NODES * HID * 4;

  // ---- CSR build (shared by both layers) + normalization ----
  hipMemsetAsync(degi, 0, N_NODES * sizeof(int), stream);
  k_deg<<<(N_EDGES + 255) / 256, 256, 0, stream>>>(ei + N_EDGES, degi);
  k_scan<<<1, 256, 0, stream>>>(degi, rowptr);
  k_dinv<<<(N_NODES + 255) / 256, 256, 0, stream>>>(degi, dinv);
  hipMemcpyAsync(cursor, rowptr, N_NODES * sizeof(int), hipMemcpyDeviceToDevice, stream);
  k_fill<<<(N_EDGES + 255) / 256, 256, 0, stream>>>(ei, cursor, adj);

  // ---- layer 1: hs1 = (x@W1)*dinv ; ob = relu(dinv*(hs1 + gather) + b1) ----
  k_gemm<DIN><<<(N_NODES + 3) / 4, 256, 0, stream>>>(x, W1, dinv, hs);
  k_gather<true><<<(N_NODES + 3) / 4, 256, 0, stream>>>(hs, rowptr, adj, dinv, b1, ob);

  // ---- layer 2: hs2 = (ob@W2)*dinv ; ob = dinv*(hs2 + gather) + b2 ----
  k_gemm<HID><<<(N_NODES + 3) / 4, 256, 0, stream>>>(ob, W2, dinv, hs);
  k_gather<false><<<(N_NODES + 3) / 4, 256, 0, stream>>>(hs, rowptr, adj, dinv, b2, ob);

  // ---- pooling + head ----
  k_pool<<<N_GRAPH, 256, 0, stream>>>(ob, bat, pooled);
  k_head<<<N_GRAPH, 64, 0, stream>>>(pooled, fcW1, fcb1, fcW2, fcb2, out);
}

// Round 3
// 613.906 us; speedup vs baseline: 3.1901x; 1.6450x over previous
//
#include <hip/hip_runtime.h>

#define N_NODES 100000
#define N_EDGES 3200000
#define DIN 128
#define HID 64
#define N_GRAPH 256

#define BSHIFT 8
#define NB 391              // ceil(N_NODES / 256)
#define CHUNK 4096          // edges per k_place block
#define EPT (CHUNK / 256)   // edges per thread in k_place

// ---------------- pass 1: coarse bucket histogram ----------------
__global__ __launch_bounds__(256) void k_hist(const int* __restrict__ col,
                                              int* __restrict__ bhist) {
  __shared__ int lh[NB];
  for (int i = threadIdx.x; i < NB; i += 256) lh[i] = 0;
  __syncthreads();
  int stride = gridDim.x * 256;
  for (int e = blockIdx.x * 256 + threadIdx.x; e < N_EDGES; e += stride)
    atomicAdd(&lh[col[e] >> BSHIFT], 1);
  __syncthreads();
  for (int i = threadIdx.x; i < NB; i += 256)
    if (lh[i]) atomicAdd(&bhist[i], lh[i]);
}

// ---------------- tiny scan of bucket counts -> base & cursor ----------------
__global__ __launch_bounds__(256) void k_scanB(const int* __restrict__ bhist,
                                               int* __restrict__ bbase,
                                               int* __restrict__ bcur) {
  __shared__ int h[NB];
  __shared__ int o[NB + 1];
  for (int i = threadIdx.x; i < NB; i += 256) h[i] = bhist[i];
  __syncthreads();
  if (threadIdx.x == 0) {
    int s = 0;
    for (int i = 0; i < NB; ++i) { o[i] = s; s += h[i]; }
    o[NB] = s;
  }
  __syncthreads();
  for (int i = threadIdx.x; i <= NB; i += 256) bbase[i] = o[i];
  for (int i = threadIdx.x; i < NB; i += 256) bcur[i] = o[i];
}

// ---------------- pass 2: place (src,dst) pairs grouped by bucket ----------------
__global__ __launch_bounds__(256) void k_place(const int* __restrict__ ei,
                                               int* __restrict__ bcur,
                                               int2* __restrict__ pairs) {
  __shared__ int lh[NB], lbase[NB], lcur[NB];
  for (int i = threadIdx.x; i < NB; i += 256) { lh[i] = 0; lcur[i] = 0; }
  __syncthreads();
  int base = blockIdx.x * CHUNK;
  int srcs[EPT], dsts[EPT];
#pragma unroll
  for (int k = 0; k < EPT; ++k) {
    int e = base + k * 256 + threadIdx.x;
    if (e < N_EDGES) {
      srcs[k] = ei[e];
      dsts[k] = ei[N_EDGES + e];
      atomicAdd(&lh[dsts[k] >> BSHIFT], 1);
    } else {
      dsts[k] = -1;
    }
  }
  __syncthreads();
  for (int i = threadIdx.x; i < NB; i += 256)
    lbase[i] = lh[i] ? atomicAdd(&bcur[i], lh[i]) : 0;
  __syncthreads();
#pragma unroll
  for (int k = 0; k < EPT; ++k) {
    if (dsts[k] >= 0) {
      int b = dsts[k] >> BSHIFT;
      int l = atomicAdd(&lcur[b], 1);
      pairs[lbase[b] + l] = make_int2(srcs[k], dsts[k]);
    }
  }
}

// ---------------- pass 3: per-bucket CSR build + degree/dinv ----------------
__global__ __launch_bounds__(256) void k_build(const int2* __restrict__ pairs,
                                               const int* __restrict__ bbase,
                                               int* __restrict__ rowptr,
                                               int* __restrict__ adj,
                                               float* __restrict__ dinv) {
  int b = blockIdx.x;
  int t = threadIdx.x;
  __shared__ int lh[256], lsc[256], lcur[256];
  __shared__ int wsum[4];
  lh[t] = 0;
  lcur[t] = 0;
  __syncthreads();
  int s0 = bbase[b], s1 = bbase[b + 1];
  for (int j = s0 + t; j < s1; j += 256) {
    int2 p = pairs[j];
    atomicAdd(&lh[p.y & 255], 1);
  }
  __syncthreads();
  // exclusive scan of lh across 256 threads
  int v = lh[t];
  int lane = t & 63, wv = t >> 6;
  int s = v;
#pragma unroll
  for (int off = 1; off < 64; off <<= 1) {
    int u = __shfl_up(s, off);
    if (lane >= off) s += u;
  }
  if (lane == 63) wsum[wv] = s;
  __syncthreads();
  int pre = 0;
  for (int w = 0; w < wv; ++w) pre += wsum[w];
  lsc[t] = pre + s - v;  // exclusive prefix
  __syncthreads();
  int node = (b << BSHIFT) + t;
  if (node < N_NODES) {
    rowptr[node] = s0 + lsc[t];
    dinv[node] = rsqrtf((float)(v + 1));  // +1 self loop
  }
  if (b == NB - 1 && t == 0) rowptr[N_NODES] = N_EDGES;
  __syncthreads();
  for (int j = s0 + t; j < s1; j += 256) {
    int2 p = pairs[j];
    int d = p.y & 255;
    int l = atomicAdd(&lcur[d], 1);
    adj[s0 + lsc[d] + l] = p.x;
  }
}

// ---------------- dense GEMM: Hs[row,:] = (X[row,:] @ W) * dinv[row] ----------------
template <int K>
__global__ __launch_bounds__(256) void k_gemm(const float* __restrict__ X,
                                              const float* __restrict__ W,
                                              const float* __restrict__ dinv,
                                              float* __restrict__ Hs) {
  __shared__ float Wl[K * HID];
  __shared__ float Xl[4][K];
  for (int i = threadIdx.x; i < K * HID; i += 256) Wl[i] = W[i];
  int row0 = blockIdx.x * 4;
  for (int i = threadIdx.x; i < 4 * K; i += 256) {
    int r = i / K, k = i - r * K;
    int row = row0 + r;
    Xl[r][k] = (row < N_NODES) ? X[(long)row * K + k] : 0.f;
  }
  __syncthreads();
  int wave = threadIdx.x >> 6, lane = threadIdx.x & 63;
  int row = row0 + wave;
  if (row >= N_NODES) return;
  float acc = 0.f;
#pragma unroll
  for (int k = 0; k < K; ++k) acc += Xl[wave][k] * Wl[k * HID + lane];
  Hs[(long)row * HID + lane] = acc * dinv[row];
}

// ------- gather: out[n] = act( dinv[n] * (hs[n] + sum_{src in adj[n]} hs[src]) + b ) -------
template <bool RELU>
__global__ __launch_bounds__(256) void k_gather(const float* __restrict__ hs,
                                                const int* __restrict__ rowptr,
                                                const int* __restrict__ adj,
                                                const float* __restrict__ dinv,
                                                const float* __restrict__ b,
                                                float* __restrict__ outb) {
  int n = blockIdx.x * 4 + (threadIdx.x >> 6);
  if (n >= N_NODES) return;
  int lane = threadIdx.x & 63;
  int s0 = rowptr[n], e0 = rowptr[n + 1];
  float acc = hs[(n << 6) + lane];  // self loop
  for (int j = s0; j < e0; j += 64) {
    int cnt = min(64, e0 - j);
    int myadj = (lane < cnt) ? adj[j + lane] : 0;
    int t = 0;
    for (; t + 4 <= cnt; t += 4) {
      int a0 = __shfl(myadj, t + 0);
      int a1 = __shfl(myadj, t + 1);
      int a2 = __shfl(myadj, t + 2);
      int a3 = __shfl(myadj, t + 3);
      float f0 = hs[(a0 << 6) + lane];
      float f1 = hs[(a1 << 6) + lane];
      float f2 = hs[(a2 << 6) + lane];
      float f3 = hs[(a3 << 6) + lane];
      acc += f0;
      acc += f1;
      acc += f2;
      acc += f3;
    }
    for (; t < cnt; ++t) {
      int a = __shfl(myadj, t);
      acc += hs[(a << 6) + lane];
    }
  }
  float v = dinv[n] * acc + b[lane];
  if (RELU) v = fmaxf(v, 0.f);
  outb[(n << 6) + lane] = v;
}

// ---------------- pooling: mean + max per sorted-batch segment ----------------
__global__ __launch_bounds__(256) void k_pool(const float* __restrict__ Hf,
                                              const int* __restrict__ batch,
                                              float* __restrict__ pooled) {
  int g = blockIdx.x;
  int start, end;
  {
    int lo = 0, hi = N_NODES;
    while (lo < hi) { int mid = (lo + hi) >> 1; if (batch[mid] < g) lo = mid + 1; else hi = mid; }
    start = lo;
    lo = start; hi = N_NODES;
    while (lo < hi) { int mid = (lo + hi) >> 1; if (batch[mid] < g + 1) lo = mid + 1; else hi = mid; }
    end = lo;
  }
  int lane = threadIdx.x & 63, wave = threadIdx.x >> 6;
  float sum = 0.f, mx = -INFINITY;
  for (int n = start + wave; n < end; n += 4) {
    float v = Hf[(n << 6) + lane];
    sum += v;
    mx = fmaxf(mx, v);
  }
  __shared__ float ssum[4][HID];
  __shared__ float smax[4][HID];
  ssum[wave][lane] = sum;
  smax[wave][lane] = mx;
  __syncthreads();
  if (wave == 0) {
    sum = ssum[0][lane] + ssum[1][lane] + ssum[2][lane] + ssum[3][lane];
    mx = fmaxf(fmaxf(smax[0][lane], smax[1][lane]), fmaxf(smax[2][lane], smax[3][lane]));
    int cnt = end - start;
    float mean;
    if (cnt == 0) { mean = 0.f; mx = 0.f; }
    else mean = sum / (float)cnt;
    pooled[g * 2 * HID + lane] = mean;
    pooled[g * 2 * HID + HID + lane] = mx;
  }
}

// ---------------- MLP head ----------------
__global__ __launch_bounds__(64) void k_head(const float* __restrict__ pooled,
                                             const float* __restrict__ fcW1,
                                             const float* __restrict__ fcb1,
                                             const float* __restrict__ fcW2,
                                             const float* __restrict__ fcb2,
                                             float* __restrict__ out) {
  int g = blockIdx.x;
  int lane = threadIdx.x;  // 64
  __shared__ float p[2 * HID];
  p[lane] = pooled[g * 2 * HID + lane];
  p[HID + lane] = pooled[g * 2 * HID + HID + lane];
  __syncthreads();
  float acc = fcb1[lane];
#pragma unroll
  for (int k = 0; k < 2 * HID; ++k) acc += p[k] * fcW1[k * HID + lane];
  acc = fmaxf(acc, 0.f);
  float contrib = acc * fcW2[lane];
#pragma unroll
  for (int off = 32; off > 0; off >>= 1) contrib += __shfl_down(contrib, off);
  if (lane == 0) out[g] = contrib + fcb2[0];
}

extern "C" void kernel_launch(void* const* d_in, const int* in_sizes, int n_in,
                              void* d_out, int out_size, void* d_ws, size_t ws_size,
                              hipStream_t stream) {
  const float* x    = (const float*)d_in[0];
  const int*   ei   = (const int*)d_in[1];
  const int*   bat  = (const int*)d_in[2];
  const float* W1   = (const float*)d_in[3];
  const float* b1   = (const float*)d_in[4];
  const float* W2   = (const float*)d_in[5];
  const float* b2   = (const float*)d_in[6];
  const float* fcW1 = (const float*)d_in[7];
  const float* fcb1 = (const float*)d_in[8];
  const float* fcW2 = (const float*)d_in[9];
  const float* fcb2 = (const float*)d_in[10];
  float* out = (float*)d_out;

  char* ws = (char*)d_ws;
  size_t off = 0;
  auto align = [&]() { off = (off + 127) & ~127ul; };
  int*   bhist  = (int*)(ws + off);   off += NB * 4;            align();
  int*   bbase  = (int*)(ws + off);   off += (NB + 1) * 4;      align();
  int*   bcur   = (int*)(ws + off);   off += NB * 4;            align();
  int*   rowptr = (int*)(ws + off);   off += (N_NODES + 1) * 4; align();
  float* dinv   = (float*)(ws + off); off += N_NODES * 4;       align();
  float* pooled = (float*)(ws + off); off += N_GRAPH * 2 * HID * 4; align();
  int*   adj    = (int*)(ws + off);   off += (size_t)N_EDGES * 4;   align();
  float* hs     = (float*)(ws + off); off += (size_t)N_NODES * HID * 4; align();
  float* ob     = (float*)(ws + off); off += (size_t)N_NODES * HID * 4;
  int2*  pairs  = (int2*)ob;  // alias: pairs dead before first write of ob

  // ---- CSR build (shared by both layers) + dinv ----
  hipMemsetAsync(bhist, 0, NB * sizeof(int), stream);
  k_hist<<<400, 256, 0, stream>>>(ei + N_EDGES, bhist);
  k_scanB<<<1, 256, 0, stream>>>(bhist, bbase, bcur);
  k_place<<<(N_EDGES + CHUNK - 1) / CHUNK, 256, 0, stream>>>(ei, bcur, pairs);
  k_build<<<NB, 256, 0, stream>>>(pairs, bbase, rowptr, adj, dinv);

  // ---- layer 1: hs1 = (x@W1)*dinv ; ob = relu(dinv*(hs1 + gather) + b1) ----
  k_gemm<DIN><<<(N_NODES + 3) / 4, 256, 0, stream>>>(x, W1, dinv, hs);
  k_gather<true><<<(N_NODES + 3) / 4, 256, 0, stream>>>(hs, rowptr, adj, dinv, b1, ob);

  // ---- layer 2: hs2 = (ob@W2)*dinv ; ob = dinv*(hs2 + gather) + b2 ----
  k_gemm<HID><<<(N_NODES + 3) / 4, 256, 0, stream>>>(ob, W2, dinv, hs);
  k_gather<false><<<(N_NODES + 3) / 4, 256, 0, stream>>>(hs, rowptr, adj, dinv, b2, ob);

  // ---- pooling + head ----
  k_pool<<<N_GRAPH, 256, 0, stream>>>(ob, bat, pooled);
  k_head<<<N_GRAPH, 64, 0, stream>>>(pooled, fcW1, fcb1, fcW2, fcb2, out);
}

// Round 5
// 499.483 us; speedup vs baseline: 3.9209x; 1.2291x over previous
//
#include <hip/hip_runtime.h>

#define N_NODES 100000
#define N_EDGES 3200000
#define DIN 128
#define HID 64
#define N_GRAPH 256

#define BSHIFT 8
#define NB 391              // ceil(N_NODES / 256)
#define CHUNK 4096          // edges per k_place block
#define EPT (CHUNK / 256)   // edges per thread in k_place

typedef __attribute__((ext_vector_type(8))) short bf16x8;
typedef __attribute__((ext_vector_type(4))) float f32x4;

__device__ inline short bf16_rne(float x) {
  union { float f; unsigned u; } a; a.f = x;
  unsigned r = (a.u + 0x7fffu + ((a.u >> 16) & 1u)) >> 16;
  return (short)r;
}
__device__ inline float bf16_to_f(short h) {
  union { unsigned u; float f; } b; b.u = ((unsigned)(unsigned short)h) << 16;
  return b.f;
}

// ---------------- pass 1: coarse bucket histogram ----------------
__global__ __launch_bounds__(256) void k_hist(const int* __restrict__ col,
                                              int* __restrict__ bhist) {
  __shared__ int lh[NB];
  for (int i = threadIdx.x; i < NB; i += 256) lh[i] = 0;
  __syncthreads();
  int stride = gridDim.x * 256;
  for (int e = blockIdx.x * 256 + threadIdx.x; e < N_EDGES; e += stride)
    atomicAdd(&lh[col[e] >> BSHIFT], 1);
  __syncthreads();
  for (int i = threadIdx.x; i < NB; i += 256)
    if (lh[i]) atomicAdd(&bhist[i], lh[i]);
}

// ---------------- tiny scan of bucket counts -> base & cursor ----------------
__global__ __launch_bounds__(256) void k_scanB(const int* __restrict__ bhist,
                                               int* __restrict__ bbase,
                                               int* __restrict__ bcur) {
  __shared__ int h[NB];
  __shared__ int o[NB + 1];
  for (int i = threadIdx.x; i < NB; i += 256) h[i] = bhist[i];
  __syncthreads();
  if (threadIdx.x == 0) {
    int s = 0;
    for (int i = 0; i < NB; ++i) { o[i] = s; s += h[i]; }
    o[NB] = s;
  }
  __syncthreads();
  for (int i = threadIdx.x; i <= NB; i += 256) bbase[i] = o[i];
  for (int i = threadIdx.x; i < NB; i += 256) bcur[i] = o[i];
}

// ---------------- pass 2: place (src,dst) pairs grouped by bucket ----------------
__global__ __launch_bounds__(256) void k_place(const int* __restrict__ ei,
                                               int* __restrict__ bcur,
                                               int2* __restrict__ pairs) {
  __shared__ int lh[NB], lbase[NB], lcur[NB];
  for (int i = threadIdx.x; i < NB; i += 256) { lh[i] = 0; lcur[i] = 0; }
  __syncthreads();
  int base = blockIdx.x * CHUNK;
  int srcs[EPT], dsts[EPT];
#pragma unroll
  for (int k = 0; k < EPT; ++k) {
    int e = base + k * 256 + threadIdx.x;
    if (e < N_EDGES) {
      srcs[k] = ei[e];
      dsts[k] = ei[N_EDGES + e];
      atomicAdd(&lh[dsts[k] >> BSHIFT], 1);
    } else {
      dsts[k] = -1;
    }
  }
  __syncthreads();
  for (int i = threadIdx.x; i < NB; i += 256)
    lbase[i] = lh[i] ? atomicAdd(&bcur[i], lh[i]) : 0;
  __syncthreads();
#pragma unroll
  for (int k = 0; k < EPT; ++k) {
    if (dsts[k] >= 0) {
      int b = dsts[k] >> BSHIFT;
      int l = atomicAdd(&lcur[b], 1);
      pairs[lbase[b] + l] = make_int2(srcs[k], dsts[k]);
    }
  }
}

// ---------------- pass 3: per-bucket CSR build + degree/dinv ----------------
__global__ __launch_bounds__(256) void k_build(const int2* __restrict__ pairs,
                                               const int* __restrict__ bbase,
                                               int* __restrict__ rowptr,
                                               int* __restrict__ adj,
                                               float* __restrict__ dinv) {
  int b = blockIdx.x;
  int t = threadIdx.x;
  __shared__ int lh[256], lsc[256], lcur[256];
  __shared__ int wsum[4];
  lh[t] = 0;
  lcur[t] = 0;
  __syncthreads();
  int s0 = bbase[b], s1 = bbase[b + 1];
  for (int j = s0 + t; j < s1; j += 256) {
    int2 p = pairs[j];
    atomicAdd(&lh[p.y & 255], 1);
  }
  __syncthreads();
  int v = lh[t];
  int lane = t & 63, wv = t >> 6;
  int s = v;
#pragma unroll
  for (int off = 1; off < 64; off <<= 1) {
    int u = __shfl_up(s, off);
    if (lane >= off) s += u;
  }
  if (lane == 63) wsum[wv] = s;
  __syncthreads();
  int pre = 0;
  for (int w = 0; w < wv; ++w) pre += wsum[w];
  lsc[t] = pre + s - v;  // exclusive prefix
  __syncthreads();
  int node = (b << BSHIFT) + t;
  if (node < N_NODES) {
    rowptr[node] = s0 + lsc[t];
    dinv[node] = rsqrtf((float)(v + 1));  // +1 self loop
  }
  if (b == NB - 1 && t == 0) rowptr[N_NODES] = N_EDGES;
  __syncthreads();
  for (int j = s0 + t; j < s1; j += 256) {
    int2 p = pairs[j];
    int d = p.y & 255;
    int l = atomicAdd(&lcur[d], 1);
    adj[s0 + lsc[d] + l] = p.x;
  }
}

// -------- MFMA GEMM (split-bf16 f32 emulation): Hs = (X @ W) * dinv[row] --------
// block = 256 thr = 4 waves; wave w owns rows [blk*64 + w*16, +16); K in {128,64}
template <int K>
__global__ __launch_bounds__(256) void k_gemm_mfma(const float* __restrict__ X,
                                                   const float* __restrict__ W,
                                                   const float* __restrict__ dinv,
                                                   float* __restrict__ Hs) {
  __shared__ short WTh[64 * K];  // W^T hi, [n][k] bf16, XOR-swizzled
  __shared__ short WTl[64 * K];  // W^T lo
  const int t = threadIdx.x;
  constexpr int KC = K / 8;
  // ---- stage W^T split hi/lo (coalesced f32x4 reads, 16B swizzled LDS writes) ----
  if (t < 16 * KC) {
    int ng = t / KC;            // n-group of 4
    int k0 = (t % KC) * 8;
    float w[8][4];
#pragma unroll
    for (int j = 0; j < 8; ++j)
      *(f32x4*)&w[j][0] = *(const f32x4*)&W[(k0 + j) * HID + ng * 4];
#pragma unroll
    for (int c = 0; c < 4; ++c) {
      int n = ng * 4 + c;
      union { short s[8]; int4 i4; } uh, ul;
#pragma unroll
      for (int j = 0; j < 8; ++j) {
        short hi = bf16_rne(w[j][c]);
        uh.s[j] = hi;
        ul.s[j] = bf16_rne(w[j][c] - bf16_to_f(hi));
      }
      int byte = (n * K + k0) * 2;
      byte ^= ((n & 7) << 4);
      *(int4*)((char*)WTh + byte) = uh.i4;
      *(int4*)((char*)WTl + byte) = ul.i4;
    }
  }
  __syncthreads();
  const int wave = t >> 6, lane = t & 63;
  const int row0 = blockIdx.x * 64 + wave * 16;
  if (row0 >= N_NODES) return;
  const int mrow = lane & 15;  // A-row within tile / D-col within tile
  const int kq = lane >> 4;    // k-quarter
  f32x4 acc[4] = {f32x4{0,0,0,0}, f32x4{0,0,0,0}, f32x4{0,0,0,0}, f32x4{0,0,0,0}};
#pragma unroll
  for (int kk = 0; kk < K; kk += 32) {
    int k0 = kk + kq * 8;
    const float* xp = &X[(long)(row0 + mrow) * K + k0];
    f32x4 v0 = *(const f32x4*)xp;
    f32x4 v1 = *(const f32x4*)(xp + 4);
    union { short s[8]; bf16x8 v; } ah, al;
#pragma unroll
    for (int j = 0; j < 4; ++j) {
      short h0 = bf16_rne(v0[j]);
      ah.s[j] = h0;
      al.s[j] = bf16_rne(v0[j] - bf16_to_f(h0));
      short h1 = bf16_rne(v1[j]);
      ah.s[4 + j] = h1;
      al.s[4 + j] = bf16_rne(v1[j] - bf16_to_f(h1));
    }
#pragma unroll
    for (int nt = 0; nt < 4; ++nt) {
      int n = nt * 16 + mrow;
      int byte = (n * K + k0) * 2;
      byte ^= ((n & 7) << 4);
      bf16x8 bh = *(bf16x8*)((char*)WTh + byte);
      bf16x8 bl = *(bf16x8*)((char*)WTl + byte);
      acc[nt] = __builtin_amdgcn_mfma_f32_16x16x32_bf16(ah.v, bh, acc[nt], 0, 0, 0);
      acc[nt] = __builtin_amdgcn_mfma_f32_16x16x32_bf16(ah.v, bl, acc[nt], 0, 0, 0);
      acc[nt] = __builtin_amdgcn_mfma_f32_16x16x32_bf16(al.v, bh, acc[nt], 0, 0, 0);
    }
  }
  // D: col = nt*16 + (lane&15), row = kq*4 + r  [measured m89 layout]
#pragma unroll
  for (int r = 0; r < 4; ++r) {
    int row = row0 + kq * 4 + r;
    float dv = dinv[row];
#pragma unroll
    for (int nt = 0; nt < 4; ++nt)
      Hs[(long)row * HID + nt * 16 + mrow] = acc[nt][r] * dv;
  }
}

// ------- gather: out[n] = act( dinv[n] * (hs[n] + sum_{src in adj[n]} hs[src]) + b ) -------
template <bool RELU>
__global__ __launch_bounds__(256) void k_gather(const float* __restrict__ hs,
                                                const int* __restrict__ rowptr,
                                                const int* __restrict__ adj,
                                                const float* __restrict__ dinv,
                                                const float* __restrict__ b,
                                                float* __restrict__ outb) {
  int n = blockIdx.x * 4 + (threadIdx.x >> 6);
  if (n >= N_NODES) return;
  int lane = threadIdx.x & 63;
  int s0 = rowptr[n], e0 = rowptr[n + 1];
  float acc = hs[(n << 6) + lane];  // self loop
  for (int j = s0; j < e0; j += 64) {
    int cnt = min(64, e0 - j);
    int myadj = (lane < cnt) ? adj[j + lane] : 0;
    int t = 0;
    for (; t + 4 <= cnt; t += 4) {
      int a0 = __shfl(myadj, t + 0);
      int a1 = __shfl(myadj, t + 1);
      int a2 = __shfl(myadj, t + 2);
      int a3 = __shfl(myadj, t + 3);
      float f0 = hs[(a0 << 6) + lane];
      float f1 = hs[(a1 << 6) + lane];
      float f2 = hs[(a2 << 6) + lane];
      float f3 = hs[(a3 << 6) + lane];
      acc += f0;
      acc += f1;
      acc += f2;
      acc += f3;
    }
    for (; t < cnt; ++t) {
      int a = __shfl(myadj, t);
      acc += hs[(a << 6) + lane];
    }
  }
  float v = dinv[n] * acc + b[lane];
  if (RELU) v = fmaxf(v, 0.f);
  outb[(n << 6) + lane] = v;
}

// ---------------- pooling: mean + max per sorted-batch segment ----------------
__global__ __launch_bounds__(256) void k_pool(const float* __restrict__ Hf,
                                              const int* __restrict__ batch,
                                              float* __restrict__ pooled) {
  int g = blockIdx.x;
  int start, end;
  {
    int lo = 0, hi = N_NODES;
    while (lo < hi) { int mid = (lo + hi) >> 1; if (batch[mid] < g) lo = mid + 1; else hi = mid; }
    start = lo;
    lo = start; hi = N_NODES;
    while (lo < hi) { int mid = (lo + hi) >> 1; if (batch[mid] < g + 1) lo = mid + 1; else hi = mid; }
    end = lo;
  }
  int lane = threadIdx.x & 63, wave = threadIdx.x >> 6;
  float sum = 0.f, mx = -INFINITY;
  for (int n = start + wave; n < end; n += 4) {
    float v = Hf[(n << 6) + lane];
    sum += v;
    mx = fmaxf(mx, v);
  }
  __shared__ float ssum[4][HID];
  __shared__ float smax[4][HID];
  ssum[wave][lane] = sum;
  smax[wave][lane] = mx;
  __syncthreads();
  if (wave == 0) {
    sum = ssum[0][lane] + ssum[1][lane] + ssum[2][lane] + ssum[3][lane];
    mx = fmaxf(fmaxf(smax[0][lane], smax[1][lane]), fmaxf(smax[2][lane], smax[3][lane]));
    int cnt = end - start;
    float mean;
    if (cnt == 0) { mean = 0.f; mx = 0.f; }
    else mean = sum / (float)cnt;
    pooled[g * 2 * HID + lane] = mean;
    pooled[g * 2 * HID + HID + lane] = mx;
  }
}

// ---------------- MLP head ----------------
__global__ __launch_bounds__(64) void k_head(const float* __restrict__ pooled,
                                             const float* __restrict__ fcW1,
                                             const float* __restrict__ fcb1,
                                             const float* __restrict__ fcW2,
                                             const float* __restrict__ fcb2,
                                             float* __restrict__ out) {
  int g = blockIdx.x;
  int lane = threadIdx.x;  // 64
  __shared__ float p[2 * HID];
  p[lane] = pooled[g * 2 * HID + lane];
  p[HID + lane] = pooled[g * 2 * HID + HID + lane];
  __syncthreads();
  float acc = fcb1[lane];
#pragma unroll
  for (int k = 0; k < 2 * HID; ++k) acc += p[k] * fcW1[k * HID + lane];
  acc = fmaxf(acc, 0.f);
  float contrib = acc * fcW2[lane];
#pragma unroll
  for (int off = 32; off > 0; off >>= 1) contrib += __shfl_down(contrib, off);
  if (lane == 0) out[g] = contrib + fcb2[0];
}

extern "C" void kernel_launch(void* const* d_in, const int* in_sizes, int n_in,
                              void* d_out, int out_size, void* d_ws, size_t ws_size,
                              hipStream_t stream) {
  const float* x    = (const float*)d_in[0];
  const int*   ei   = (const int*)d_in[1];
  const int*   bat  = (const int*)d_in[2];
  const float* W1   = (const float*)d_in[3];
  const float* b1   = (const float*)d_in[4];
  const float* W2   = (const float*)d_in[5];
  const float* b2   = (const float*)d_in[6];
  const float* fcW1 = (const float*)d_in[7];
  const float* fcb1 = (const float*)d_in[8];
  const float* fcW2 = (const float*)d_in[9];
  const float* fcb2 = (const float*)d_in[10];
  float* out = (float*)d_out;

  char* ws = (char*)d_ws;
  size_t off = 0;
  auto align = [&]() { off = (off + 127) & ~127ul; };
  int*   bhist  = (int*)(ws + off);   off += NB * 4;            align();
  int*   bbase  = (int*)(ws + off);   off += (NB + 1) * 4;      align();
  int*   bcur   = (int*)(ws + off);   off += NB * 4;            align();
  int*   rowptr = (int*)(ws + off);   off += (N_NODES + 1) * 4; align();
  float* dinv   = (float*)(ws + off); off += N_NODES * 4;       align();
  float* pooled = (float*)(ws + off); off += N_GRAPH * 2 * HID * 4; align();
  int*   adj    = (int*)(ws + off);   off += (size_t)N_EDGES * 4;   align();
  float* hs     = (float*)(ws + off); off += (size_t)N_NODES * HID * 4; align();
  float* ob     = (float*)(ws + off); off += (size_t)N_NODES * HID * 4;
  int2*  pairs  = (int2*)ob;  // alias: pairs dead before first write of ob

  // ---- CSR build (shared by both layers) + dinv ----
  hipMemsetAsync(bhist, 0, NB * sizeof(int), stream);
  k_hist<<<400, 256, 0, stream>>>(ei + N_EDGES, bhist);
  k_scanB<<<1, 256, 0, stream>>>(bhist, bbase, bcur);
  k_place<<<(N_EDGES + CHUNK - 1) / CHUNK, 256, 0, stream>>>(ei, bcur, pairs);
  k_build<<<NB, 256, 0, stream>>>(pairs, bbase, rowptr, adj, dinv);

  // ---- layer 1: hs1 = (x@W1)*dinv ; ob = relu(dinv*(hs1 + gather) + b1) ----
  k_gemm_mfma<DIN><<<(N_NODES + 63) / 64, 256, 0, stream>>>(x, W1, dinv, hs);
  k_gather<true><<<(N_NODES + 3) / 4, 256, 0, stream>>>(hs, rowptr, adj, dinv, b1, ob);

  // ---- layer 2: hs2 = (ob@W2)*dinv ; ob = dinv*(hs2 + gather) + b2 ----
  k_gemm_mfma<HID><<<(N_NODES + 63) / 64, 256, 0, stream>>>(ob, W2, dinv, hs);
  k_gather<false><<<(N_NODES + 3) / 4, 256, 0, stream>>>(hs, rowptr, adj, dinv, b2, ob);

  // ---- pooling + head ----
  k_pool<<<N_GRAPH, 256, 0, stream>>>(ob, bat, pooled);
  k_head<<<N_GRAPH, 64, 0, stream>>>(pooled, fcW1, fcb1, fcW2, fcb2, out);
}

// Round 6
// 428.175 us; speedup vs baseline: 4.5739x; 1.1665x over previous
//
#include <hip/hip_runtime.h>

#define N_NODES 100000
#define N_EDGES 3200000
#define DIN 128
#define HID 64
#define N_GRAPH 256

#define BSHIFT 8
#define NB 391              // ceil(N_NODES / 256)
#define CHUNK 4096          // edges per k_place block
#define EPT (CHUNK / 256)   // edges per thread in k_place

typedef __attribute__((ext_vector_type(8))) short bf16x8;
typedef __attribute__((ext_vector_type(4))) float f32x4;

__device__ inline short bf16_rne(float x) {
  union { float f; unsigned u; } a; a.f = x;
  unsigned r = (a.u + 0x7fffu + ((a.u >> 16) & 1u)) >> 16;
  return (short)r;
}
__device__ inline float bf16_to_f(unsigned short h) {
  union { unsigned u; float f; } b; b.u = ((unsigned)h) << 16;
  return b.f;
}

// ---------------- pass 1: coarse bucket histogram ----------------
__global__ __launch_bounds__(256) void k_hist(const int* __restrict__ col,
                                              int* __restrict__ bhist) {
  __shared__ int lh[NB];
  for (int i = threadIdx.x; i < NB; i += 256) lh[i] = 0;
  __syncthreads();
  int stride = gridDim.x * 256;
  for (int e = blockIdx.x * 256 + threadIdx.x; e < N_EDGES; e += stride)
    atomicAdd(&lh[col[e] >> BSHIFT], 1);
  __syncthreads();
  for (int i = threadIdx.x; i < NB; i += 256)
    if (lh[i]) atomicAdd(&bhist[i], lh[i]);
}

// ---------------- tiny scan of bucket counts -> base & cursor ----------------
__global__ __launch_bounds__(256) void k_scanB(const int* __restrict__ bhist,
                                               int* __restrict__ bbase,
                                               int* __restrict__ bcur) {
  __shared__ int h[NB];
  __shared__ int o[NB + 1];
  for (int i = threadIdx.x; i < NB; i += 256) h[i] = bhist[i];
  __syncthreads();
  if (threadIdx.x == 0) {
    int s = 0;
    for (int i = 0; i < NB; ++i) { o[i] = s; s += h[i]; }
    o[NB] = s;
  }
  __syncthreads();
  for (int i = threadIdx.x; i <= NB; i += 256) bbase[i] = o[i];
  for (int i = threadIdx.x; i < NB; i += 256) bcur[i] = o[i];
}

// ------- pass 2: place packed (src<<8 | dst&255) grouped by bucket -------
__global__ __launch_bounds__(256) void k_place(const int* __restrict__ ei,
                                               int* __restrict__ bcur,
                                               int* __restrict__ pairs) {
  __shared__ int lh[NB], lbase[NB], lcur[NB];
  for (int i = threadIdx.x; i < NB; i += 256) { lh[i] = 0; lcur[i] = 0; }
  __syncthreads();
  int base = blockIdx.x * CHUNK;
  int srcs[EPT], dsts[EPT];
#pragma unroll
  for (int k = 0; k < EPT; ++k) {
    int e = base + k * 256 + threadIdx.x;
    if (e < N_EDGES) {
      srcs[k] = ei[e];
      dsts[k] = ei[N_EDGES + e];
      atomicAdd(&lh[dsts[k] >> BSHIFT], 1);
    } else {
      dsts[k] = -1;
    }
  }
  __syncthreads();
  for (int i = threadIdx.x; i < NB; i += 256)
    lbase[i] = lh[i] ? atomicAdd(&bcur[i], lh[i]) : 0;
  __syncthreads();
#pragma unroll
  for (int k = 0; k < EPT; ++k) {
    if (dsts[k] >= 0) {
      int b = dsts[k] >> BSHIFT;
      int l = atomicAdd(&lcur[b], 1);
      pairs[lbase[b] + l] = (srcs[k] << 8) | (dsts[k] & 255);
    }
  }
}

// ---------------- pass 3: per-bucket CSR build + degree/dinv ----------------
__global__ __launch_bounds__(256) void k_build(const int* __restrict__ pairs,
                                               const int* __restrict__ bbase,
                                               int* __restrict__ rowptr,
                                               int* __restrict__ adj,
                                               float* __restrict__ dinv) {
  int b = blockIdx.x;
  int t = threadIdx.x;
  __shared__ int lh[256], lsc[256], lcur[256];
  __shared__ int wsum[4];
  lh[t] = 0;
  lcur[t] = 0;
  __syncthreads();
  int s0 = bbase[b], s1 = bbase[b + 1];
  for (int j = s0 + t; j < s1; j += 256) {
    int p = pairs[j];
    atomicAdd(&lh[p & 255], 1);
  }
  __syncthreads();
  int v = lh[t];
  int lane = t & 63, wv = t >> 6;
  int s = v;
#pragma unroll
  for (int off = 1; off < 64; off <<= 1) {
    int u = __shfl_up(s, off);
    if (lane >= off) s += u;
  }
  if (lane == 63) wsum[wv] = s;
  __syncthreads();
  int pre = 0;
  for (int w = 0; w < wv; ++w) pre += wsum[w];
  lsc[t] = pre + s - v;  // exclusive prefix
  __syncthreads();
  int node = (b << BSHIFT) + t;
  if (node < N_NODES) {
    rowptr[node] = s0 + lsc[t];
    dinv[node] = rsqrtf((float)(v + 1));  // +1 self loop
  }
  if (b == NB - 1 && t == 0) rowptr[N_NODES] = N_EDGES;
  __syncthreads();
  for (int j = s0 + t; j < s1; j += 256) {
    int p = pairs[j];
    int d = p & 255;
    int l = atomicAdd(&lcur[d], 1);
    adj[s0 + lsc[d] + l] = p >> 8;
  }
}

// -------- MFMA GEMM (split-bf16 f32 emulation): Hs = bf16((X @ W) * dinv[row]) --------
// block = 256 thr = 4 waves; wave w owns rows [blk*64 + w*16, +16); K in {128,64}
template <int K>
__global__ __launch_bounds__(256) void k_gemm_mfma(const float* __restrict__ X,
                                                   const float* __restrict__ W,
                                                   const float* __restrict__ dinv,
                                                   unsigned short* __restrict__ Hs) {
  __shared__ short WTh[64 * K];  // W^T hi, [n][k] bf16, XOR-swizzled
  __shared__ short WTl[64 * K];  // W^T lo
  const int t = threadIdx.x;
  constexpr int KC = K / 8;
  if (t < 16 * KC) {
    int ng = t / KC;            // n-group of 4
    int k0 = (t % KC) * 8;
    float w[8][4];
#pragma unroll
    for (int j = 0; j < 8; ++j)
      *(f32x4*)&w[j][0] = *(const f32x4*)&W[(k0 + j) * HID + ng * 4];
#pragma unroll
    for (int c = 0; c < 4; ++c) {
      int n = ng * 4 + c;
      union { short s[8]; int4 i4; } uh, ul;
#pragma unroll
      for (int j = 0; j < 8; ++j) {
        short hi = bf16_rne(w[j][c]);
        uh.s[j] = hi;
        ul.s[j] = bf16_rne(w[j][c] - bf16_to_f((unsigned short)hi));
      }
      int byte = (n * K + k0) * 2;
      byte ^= ((n & 7) << 4);
      *(int4*)((char*)WTh + byte) = uh.i4;
      *(int4*)((char*)WTl + byte) = ul.i4;
    }
  }
  __syncthreads();
  const int wave = t >> 6, lane = t & 63;
  const int row0 = blockIdx.x * 64 + wave * 16;
  if (row0 >= N_NODES) return;
  const int mrow = lane & 15;  // A-row within tile / D-col within tile
  const int kq = lane >> 4;    // k-quarter
  f32x4 acc[4] = {f32x4{0,0,0,0}, f32x4{0,0,0,0}, f32x4{0,0,0,0}, f32x4{0,0,0,0}};
#pragma unroll
  for (int kk = 0; kk < K; kk += 32) {
    int k0 = kk + kq * 8;
    const float* xp = &X[(long)(row0 + mrow) * K + k0];
    f32x4 v0 = *(const f32x4*)xp;
    f32x4 v1 = *(const f32x4*)(xp + 4);
    union { short s[8]; bf16x8 v; } ah, al;
#pragma unroll
    for (int j = 0; j < 4; ++j) {
      short h0 = bf16_rne(v0[j]);
      ah.s[j] = h0;
      al.s[j] = bf16_rne(v0[j] - bf16_to_f((unsigned short)h0));
      short h1 = bf16_rne(v1[j]);
      ah.s[4 + j] = h1;
      al.s[4 + j] = bf16_rne(v1[j] - bf16_to_f((unsigned short)h1));
    }
#pragma unroll
    for (int nt = 0; nt < 4; ++nt) {
      int n = nt * 16 + mrow;
      int byte = (n * K + k0) * 2;
      byte ^= ((n & 7) << 4);
      bf16x8 bh = *(bf16x8*)((char*)WTh + byte);
      bf16x8 bl = *(bf16x8*)((char*)WTl + byte);
      acc[nt] = __builtin_amdgcn_mfma_f32_16x16x32_bf16(ah.v, bh, acc[nt], 0, 0, 0);
      acc[nt] = __builtin_amdgcn_mfma_f32_16x16x32_bf16(ah.v, bl, acc[nt], 0, 0, 0);
      acc[nt] = __builtin_amdgcn_mfma_f32_16x16x32_bf16(al.v, bh, acc[nt], 0, 0, 0);
    }
  }
  // D: col = nt*16 + (lane&15), row = kq*4 + r  [measured m89 layout]
#pragma unroll
  for (int r = 0; r < 4; ++r) {
    int row = row0 + kq * 4 + r;
    float dv = dinv[row];
#pragma unroll
    for (int nt = 0; nt < 4; ++nt)
      Hs[((long)row << 6) + nt * 16 + mrow] = (unsigned short)bf16_rne(acc[nt][r] * dv);
  }
}

// ------- gather: out[n] = act( dinv[n] * (hs[n] + sum_{src in adj[n]} hs[src]) + b ) -------
template <bool RELU>
__global__ __launch_bounds__(256) void k_gather(const unsigned short* __restrict__ hs,
                                                const int* __restrict__ rowptr,
                                                const int* __restrict__ adj,
                                                const float* __restrict__ dinv,
                                                const float* __restrict__ b,
                                                float* __restrict__ outb) {
  int n = blockIdx.x * 4 + (threadIdx.x >> 6);
  if (n >= N_NODES) return;
  int lane = threadIdx.x & 63;
  int s0 = rowptr[n], e0 = rowptr[n + 1];
  float acc = bf16_to_f(hs[((long)n << 6) + lane]);  // self loop
  for (int j = s0; j < e0; j += 64) {
    int cnt = min(64, e0 - j);
    int myadj = (lane < cnt) ? adj[j + lane] : 0;
    int t = 0;
    for (; t + 4 <= cnt; t += 4) {
      int a0 = __shfl(myadj, t + 0);
      int a1 = __shfl(myadj, t + 1);
      int a2 = __shfl(myadj, t + 2);
      int a3 = __shfl(myadj, t + 3);
      float f0 = bf16_to_f(hs[((long)a0 << 6) + lane]);
      float f1 = bf16_to_f(hs[((long)a1 << 6) + lane]);
      float f2 = bf16_to_f(hs[((long)a2 << 6) + lane]);
      float f3 = bf16_to_f(hs[((long)a3 << 6) + lane]);
      acc += f0;
      acc += f1;
      acc += f2;
      acc += f3;
    }
    for (; t < cnt; ++t) {
      int a = __shfl(myadj, t);
      acc += bf16_to_f(hs[((long)a << 6) + lane]);
    }
  }
  float v = dinv[n] * acc + b[lane];
  if (RELU) v = fmaxf(v, 0.f);
  outb[((long)n << 6) + lane] = v;
}

// ---------------- pooling: mean + max per sorted-batch segment ----------------
__global__ __launch_bounds__(256) void k_pool(const float* __restrict__ Hf,
                                              const int* __restrict__ batch,
                                              float* __restrict__ pooled) {
  int g = blockIdx.x;
  int start, end;
  {
    int lo = 0, hi = N_NODES;
    while (lo < hi) { int mid = (lo + hi) >> 1; if (batch[mid] < g) lo = mid + 1; else hi = mid; }
    start = lo;
    lo = start; hi = N_NODES;
    while (lo < hi) { int mid = (lo + hi) >> 1; if (batch[mid] < g + 1) lo = mid + 1; else hi = mid; }
    end = lo;
  }
  int lane = threadIdx.x & 63, wave = threadIdx.x >> 6;
  float sum = 0.f, mx = -INFINITY;
  for (int n = start + wave; n < end; n += 4) {
    float v = Hf[((long)n << 6) + lane];
    sum += v;
    mx = fmaxf(mx, v);
  }
  __shared__ float ssum[4][HID];
  __shared__ float smax[4][HID];
  ssum[wave][lane] = sum;
  smax[wave][lane] = mx;
  __syncthreads();
  if (wave == 0) {
    sum = ssum[0][lane] + ssum[1][lane] + ssum[2][lane] + ssum[3][lane];
    mx = fmaxf(fmaxf(smax[0][lane], smax[1][lane]), fmaxf(smax[2][lane], smax[3][lane]));
    int cnt = end - start;
    float mean;
    if (cnt == 0) { mean = 0.f; mx = 0.f; }
    else mean = sum / (float)cnt;
    pooled[g * 2 * HID + lane] = mean;
    pooled[g * 2 * HID + HID + lane] = mx;
  }
}

// ---------------- MLP head ----------------
__global__ __launch_bounds__(64) void k_head(const float* __restrict__ pooled,
                                             const float* __restrict__ fcW1,
                                             const float* __restrict__ fcb1,
                                             const float* __restrict__ fcW2,
                                             const float* __restrict__ fcb2,
                                             float* __restrict__ out) {
  int g = blockIdx.x;
  int lane = threadIdx.x;  // 64
  __shared__ float p[2 * HID];
  p[lane] = pooled[g * 2 * HID + lane];
  p[HID + lane] = pooled[g * 2 * HID + HID + lane];
  __syncthreads();
  float acc = fcb1[lane];
#pragma unroll
  for (int k = 0; k < 2 * HID; ++k) acc += p[k] * fcW1[k * HID + lane];
  acc = fmaxf(acc, 0.f);
  float contrib = acc * fcW2[lane];
#pragma unroll
  for (int off = 32; off > 0; off >>= 1) contrib += __shfl_down(contrib, off);
  if (lane == 0) out[g] = contrib + fcb2[0];
}

extern "C" void kernel_launch(void* const* d_in, const int* in_sizes, int n_in,
                              void* d_out, int out_size, void* d_ws, size_t ws_size,
                              hipStream_t stream) {
  const float* x    = (const float*)d_in[0];
  const int*   ei   = (const int*)d_in[1];
  const int*   bat  = (const int*)d_in[2];
  const float* W1   = (const float*)d_in[3];
  const float* b1   = (const float*)d_in[4];
  const float* W2   = (const float*)d_in[5];
  const float* b2   = (const float*)d_in[6];
  const float* fcW1 = (const float*)d_in[7];
  const float* fcb1 = (const float*)d_in[8];
  const float* fcW2 = (const float*)d_in[9];
  const float* fcb2 = (const float*)d_in[10];
  float* out = (float*)d_out;

  char* ws = (char*)d_ws;
  size_t off = 0;
  auto align = [&]() { off = (off + 127) & ~127ul; };
  int*   bhist  = (int*)(ws + off);   off += NB * 4;            align();
  int*   bbase  = (int*)(ws + off);   off += (NB + 1) * 4;      align();
  int*   bcur   = (int*)(ws + off);   off += NB * 4;            align();
  int*   rowptr = (int*)(ws + off);   off += (N_NODES + 1) * 4; align();
  float* dinv   = (float*)(ws + off); off += N_NODES * 4;       align();
  float* pooled = (float*)(ws + off); off += N_GRAPH * 2 * HID * 4; align();
  int*   adj    = (int*)(ws + off);   off += (size_t)N_EDGES * 4;   align();
  unsigned short* hs = (unsigned short*)(ws + off); off += (size_t)N_NODES * HID * 2; align();
  float* ob     = (float*)(ws + off); off += (size_t)N_NODES * HID * 4;
  int*   pairs  = (int*)ob;  // alias: pairs dead before first write of ob

  // ---- CSR build (shared by both layers) + dinv ----
  hipMemsetAsync(bhist, 0, NB * sizeof(int), stream);
  k_hist<<<400, 256, 0, stream>>>(ei + N_EDGES, bhist);
  k_scanB<<<1, 256, 0, stream>>>(bhist, bbase, bcur);
  k_place<<<(N_EDGES + CHUNK - 1) / CHUNK, 256, 0, stream>>>(ei, bcur, pairs);
  k_build<<<NB, 256, 0, stream>>>(pairs, bbase, rowptr, adj, dinv);

  // ---- layer 1: hs1 = bf16((x@W1)*dinv) ; ob = relu(dinv*(hs1 + gather) + b1) ----
  k_gemm_mfma<DIN><<<(N_NODES + 63) / 64, 256, 0, stream>>>(x, W1, dinv, hs);
  k_gather<true><<<(N_NODES + 3) / 4, 256, 0, stream>>>(hs, rowptr, adj, dinv, b1, ob);

  // ---- layer 2: hs2 = bf16((ob@W2)*dinv) ; ob = dinv*(hs2 + gather) + b2 ----
  k_gemm_mfma<HID><<<(N_NODES + 63) / 64, 256, 0, stream>>>(ob, W2, dinv, hs);
  k_gather<false><<<(N_NODES + 3) / 4, 256, 0, stream>>>(hs, rowptr, adj, dinv, b2, ob);

  // ---- pooling + head ----
  k_pool<<<N_GRAPH, 256, 0, stream>>>(ob, bat, pooled);
  k_head<<<N_GRAPH, 64, 0, stream>>>(pooled, fcW1, fcb1, fcW2, fcb2, out);
}